// Round 1
// baseline (1243.974 us; speedup 1.0000x reference)
//
#include <hip/hip_runtime.h>
#include <hip/hip_bf16.h>
#include <math.h>

typedef __bf16 bf16;
typedef __attribute__((ext_vector_type(8))) __bf16 bf16x8;
typedef __attribute__((ext_vector_type(4))) __bf16 bf16x4;
typedef __attribute__((ext_vector_type(4))) float f32x4;

#define MFMA16(a, b, c) __builtin_amdgcn_mfma_f32_16x16x32_bf16(a, b, c, 0, 0, 0)

// ---------------------------------------------------------------------------
// GEMM: C[M x N] = A[M x K] (row-major, AT = float or bf16) @ Bw[K x N] (fp32)
// 128x128 block tile, 4 waves each computing a 64x64 subtile (4x4 MFMA tiles),
// BK=32. A staged to LDS as bf16 [128][40-padded]; B transpose-staged to
// Bs[n][k] so both operands are ds_read_b128 in MFMA fragment layout.
// TRANS_OUT: write C transposed (C[n][m], ld = M) — used to produce vT.
// ---------------------------------------------------------------------------
template <typename AT, typename OT, bool TRANS_OUT>
__global__ __launch_bounds__(256, 2) void gemm_k(const AT* __restrict__ A,
                                                 const float* __restrict__ Bw,
                                                 OT* __restrict__ C, int M,
                                                 int N, int K, int ldc) {
  __shared__ bf16 As[128][40];
  __shared__ bf16 Bs[128][40];

  const int tid = threadIdx.x;
  const int lane = tid & 63;
  const int w = tid >> 6;
  const int quad = lane >> 4;
  const int m16 = lane & 15;
  const int wr = (w >> 1) * 64;  // wave row offset in tile
  const int wc = (w & 1) * 64;   // wave col offset in tile
  const int rowBase = blockIdx.y * 128;
  const int colBase = blockIdx.x * 128;

  f32x4 acc[4][4];
#pragma unroll
  for (int i = 0; i < 4; ++i)
#pragma unroll
    for (int j = 0; j < 4; ++j) acc[i][j] = (f32x4){0.f, 0.f, 0.f, 0.f};

  const int ar = tid >> 1;         // A-stage row 0..127
  const int ak = (tid & 1) * 16;   // A-stage k-offset
  const int bn = tid & 127;        // B-stage col 0..127
  const int bk = (tid >> 7) * 16;  // B-stage k-offset

  for (int k0 = 0; k0 < K; k0 += 32) {
    // ---- stage A tile (convert fp32 -> bf16 if needed) ----
    {
      const AT* ap = A + (size_t)(rowBase + ar) * K + k0 + ak;
      if constexpr (sizeof(AT) == 4) {
#pragma unroll
        for (int v = 0; v < 4; ++v) {
          f32x4 f = *(const f32x4*)(ap + v * 4);
          bf16x4 h;
          h[0] = (bf16)f[0];
          h[1] = (bf16)f[1];
          h[2] = (bf16)f[2];
          h[3] = (bf16)f[3];
          *(bf16x4*)&As[ar][ak + v * 4] = h;
        }
      } else {
        *(bf16x8*)&As[ar][ak] = *(const bf16x8*)(ap);
        *(bf16x8*)&As[ar][ak + 8] = *(const bf16x8*)(ap + 8);
      }
    }
    // ---- stage B tile transposed: Bs[n][k] = Bw[k0+k][colBase+n] ----
    {
      const float* bp = Bw + (size_t)(k0 + bk) * N + colBase + bn;
      float vals[16];
#pragma unroll
      for (int i = 0; i < 16; ++i) vals[i] = bp[(size_t)i * N];
      bf16x8 v0, v1;
#pragma unroll
      for (int i = 0; i < 8; ++i) {
        v0[i] = (bf16)vals[i];
        v1[i] = (bf16)vals[8 + i];
      }
      *(bf16x8*)&Bs[bn][bk] = v0;
      *(bf16x8*)&Bs[bn][bk + 8] = v1;
    }
    __syncthreads();

    // ---- compute: 16 MFMAs per wave per K-step ----
    bf16x8 af[4], bfr[4];
#pragma unroll
    for (int mi = 0; mi < 4; ++mi)
      af[mi] = *(const bf16x8*)&As[wr + mi * 16 + m16][quad * 8];
#pragma unroll
    for (int ni = 0; ni < 4; ++ni)
      bfr[ni] = *(const bf16x8*)&Bs[wc + ni * 16 + m16][quad * 8];
#pragma unroll
    for (int mi = 0; mi < 4; ++mi)
#pragma unroll
      for (int ni = 0; ni < 4; ++ni)
        acc[mi][ni] = MFMA16(af[mi], bfr[ni], acc[mi][ni]);
    __syncthreads();
  }

  // ---- epilogue: C/D layout col = lane&15, row = quad*4 + reg ----
#pragma unroll
  for (int mi = 0; mi < 4; ++mi) {
#pragma unroll
    for (int ni = 0; ni < 4; ++ni) {
      const int gr0 = rowBase + wr + mi * 16 + quad * 4;
      const int gc = colBase + wc + ni * 16 + m16;
      if constexpr (TRANS_OUT) {
        bf16x4 h;
#pragma unroll
        for (int r = 0; r < 4; ++r) h[r] = (bf16)acc[mi][ni][r];
        *(bf16x4*)&C[(size_t)gc * ldc + gr0] = h;
      } else {
#pragma unroll
        for (int r = 0; r < 4; ++r)
          C[(size_t)(gr0 + r) * ldc + gc] = (OT)acc[mi][ni][r];
      }
    }
  }
}

// ---------------------------------------------------------------------------
// RoPE (rotate-half, in place on bf16 q and k buffers).
// idx -> (s, head, j<64); pairs (j, j+64) share angle f = s * base^(-j/64).
// ---------------------------------------------------------------------------
__global__ __launch_bounds__(256) void rope_k(bf16* __restrict__ qb,
                                              bf16* __restrict__ kb) {
  const int NQTOT = 2048 * 32 * 64;
  const int NKTOT = 2048 * 8 * 64;
  int idx = blockIdx.x * 256 + threadIdx.x;
  bf16* buf;
  int nh, rest;
  if (idx < NQTOT) {
    buf = qb;
    nh = 32;
    rest = idx;
  } else {
    rest = idx - NQTOT;
    if (rest >= NKTOT) return;
    buf = kb;
    nh = 8;
  }
  const int j = rest & 63;
  const int hs = rest >> 6;
  const int hh = hs % nh;
  const int s = hs / nh;
  const float inv = powf(10000.0f, -(float)j * (1.0f / 64.0f));
  const float f = (float)s * inv;
  float sn, cs;
  sincosf(f, &sn, &cs);
  const size_t base = (size_t)(s * nh + hh) * 128 + j;
  const float x1 = (float)buf[base];
  const float x2 = (float)buf[base + 64];
  buf[base] = (bf16)(x1 * cs - x2 * sn);
  buf[base + 64] = (bf16)(x2 * cs + x1 * sn);
}

// ---------------------------------------------------------------------------
// Flash attention with streaming (sink + local) block mask.
// Grid: (16 q-blocks, 32 heads). Block: 256 threads = 4 waves; wave w owns
// q rows [qb*128 + 32w, +32). Keys processed in 64-wide chunks.
// Q fragments live in registers; K chunk staged [64][136]; V chunk staged
// from pre-transposed vT as Vs[d][kp]; P round-trips through LDS (wave-
// private rows, no barrier needed between write and read).
// ---------------------------------------------------------------------------
__global__ __launch_bounds__(256, 2) void attn_k(const bf16* __restrict__ q,
                                                 const bf16* __restrict__ kbuf,
                                                 const bf16* __restrict__ vT,
                                                 bf16* __restrict__ attn) {
  const int qb = blockIdx.x;
  const int h = blockIdx.y;
  const int kvh = h >> 2;  // GQA: 4 q heads per kv head
  const int tid = threadIdx.x;
  const int lane = tid & 63;
  const int w = tid >> 6;
  const int quad = lane >> 4;
  const int m16 = lane & 15;

  __shared__ bf16 Ks[64][136];
  __shared__ bf16 Vs[128][72];
  __shared__ bf16 Ps[128][72];

  const int qrow0 = qb * 128 + w * 32;

  // Q fragments (A-operand layout: m = lane&15, k = quad*8 + j)
  bf16x8 qf[2][4];
#pragma unroll
  for (int rt = 0; rt < 2; ++rt)
#pragma unroll
    for (int kt = 0; kt < 4; ++kt)
      qf[rt][kt] = *(const bf16x8*)&q[(size_t)(qrow0 + rt * 16 + m16) * 4096 +
                                      h * 128 + kt * 32 + quad * 8];

  f32x4 o[2][8];
  float mrun[2][4], lrun[2][4];
#pragma unroll
  for (int rt = 0; rt < 2; ++rt) {
#pragma unroll
    for (int dt = 0; dt < 8; ++dt) o[rt][dt] = (f32x4){0.f, 0.f, 0.f, 0.f};
#pragma unroll
    for (int r = 0; r < 4; ++r) {
      mrun[rt][r] = -1e30f;
      lrun[rt][r] = 0.f;
    }
  }

  const float scale = 0.08838834764831845f;  // 1/sqrt(128)

  for (int b = 0; b <= qb; ++b) {
    if (b > 0 && (qb - b) >= 8) continue;  // streaming mask: sink or local
    for (int half = 0; half < 2; ++half) {
      const int gk0 = b * 128 + half * 64;
      // stage K chunk: Ks[kp][d]
      {
        const int r = tid >> 2, seg = (tid & 3) * 32;
        const bf16* src = &kbuf[(size_t)(gk0 + r) * 1024 + kvh * 128 + seg];
#pragma unroll
        for (int v = 0; v < 4; ++v)
          *(bf16x8*)&Ks[r][seg + v * 8] = *(const bf16x8*)(src + v * 8);
      }
      // stage V chunk: Vs[d][kp] from vT[d_global][s]
      {
        const int d = tid >> 1, seg = (tid & 1) * 32;
        const bf16* src = &vT[(size_t)(kvh * 128 + d) * 2048 + gk0 + seg];
#pragma unroll
        for (int v = 0; v < 4; ++v)
          *(bf16x8*)&Vs[d][seg + v * 8] = *(const bf16x8*)(src + v * 8);
      }
      __syncthreads();

      // S = Q K^T for this wave's 32 rows x 64 keys
      f32x4 sc[2][4];
#pragma unroll
      for (int rt = 0; rt < 2; ++rt)
#pragma unroll
        for (int ct = 0; ct < 4; ++ct) sc[rt][ct] = (f32x4){0.f, 0.f, 0.f, 0.f};
#pragma unroll
      for (int kt = 0; kt < 4; ++kt) {
        bf16x8 bfr[4];
#pragma unroll
        for (int ct = 0; ct < 4; ++ct)
          bfr[ct] = *(const bf16x8*)&Ks[ct * 16 + m16][kt * 32 + quad * 8];
#pragma unroll
        for (int rt = 0; rt < 2; ++rt)
#pragma unroll
          for (int ct = 0; ct < 4; ++ct)
            sc[rt][ct] = MFMA16(qf[rt][kt], bfr[ct], sc[rt][ct]);
      }

      // scale + causal mask (only the diagonal block is partially masked)
#pragma unroll
      for (int rt = 0; rt < 2; ++rt)
#pragma unroll
        for (int ct = 0; ct < 4; ++ct)
#pragma unroll
          for (int r = 0; r < 4; ++r) {
            float sv = sc[rt][ct][r] * scale;
            if (b == qb) {
              const int colg = gk0 + ct * 16 + m16;
              const int rowg = qb * 128 + w * 32 + rt * 16 + quad * 4 + r;
              if (colg > rowg) sv = -1e30f;
            }
            sc[rt][ct][r] = sv;
          }

      // row max (across 4 col-tiles in-lane, then 16 lanes of the quad)
      float mb[2][4];
#pragma unroll
      for (int rt = 0; rt < 2; ++rt)
#pragma unroll
        for (int r = 0; r < 4; ++r) {
          float m = fmaxf(fmaxf(sc[rt][0][r], sc[rt][1][r]),
                          fmaxf(sc[rt][2][r], sc[rt][3][r]));
          m = fmaxf(m, __shfl_xor(m, 1));
          m = fmaxf(m, __shfl_xor(m, 2));
          m = fmaxf(m, __shfl_xor(m, 4));
          m = fmaxf(m, __shfl_xor(m, 8));
          mb[rt][r] = m;
        }

      float alpha[2][4], ls[2][4];
#pragma unroll
      for (int rt = 0; rt < 2; ++rt)
#pragma unroll
        for (int r = 0; r < 4; ++r) {
          const float mn = fmaxf(mrun[rt][r], mb[rt][r]);
          alpha[rt][r] = __expf(mrun[rt][r] - mn);
          mrun[rt][r] = mn;
          ls[rt][r] = 0.f;
        }
#pragma unroll
      for (int rt = 0; rt < 2; ++rt)
#pragma unroll
        for (int ct = 0; ct < 4; ++ct)
#pragma unroll
          for (int r = 0; r < 4; ++r) {
            const float p = __expf(sc[rt][ct][r] - mrun[rt][r]);
            sc[rt][ct][r] = p;
            ls[rt][r] += p;
          }
#pragma unroll
      for (int rt = 0; rt < 2; ++rt)
#pragma unroll
        for (int r = 0; r < 4; ++r) {
          float s = ls[rt][r];
          s += __shfl_xor(s, 1);
          s += __shfl_xor(s, 2);
          s += __shfl_xor(s, 4);
          s += __shfl_xor(s, 8);
          lrun[rt][r] = lrun[rt][r] * alpha[rt][r] + s;
        }
#pragma unroll
      for (int rt = 0; rt < 2; ++rt)
#pragma unroll
        for (int dt = 0; dt < 8; ++dt)
#pragma unroll
          for (int r = 0; r < 4; ++r) o[rt][dt][r] *= alpha[rt][r];

      // P -> LDS (C/D layout -> A-operand layout round trip; wave-private)
#pragma unroll
      for (int rt = 0; rt < 2; ++rt)
#pragma unroll
        for (int ct = 0; ct < 4; ++ct)
#pragma unroll
          for (int r = 0; r < 4; ++r)
            Ps[w * 32 + rt * 16 + quad * 4 + r][ct * 16 + m16] =
                (bf16)sc[rt][ct][r];

      // O += P V
#pragma unroll
      for (int rt = 0; rt < 2; ++rt)
#pragma unroll
        for (int kt = 0; kt < 2; ++kt) {
          const bf16x8 pa =
              *(const bf16x8*)&Ps[w * 32 + rt * 16 + m16][kt * 32 + quad * 8];
#pragma unroll
          for (int dt = 0; dt < 8; ++dt) {
            const bf16x8 vb =
                *(const bf16x8*)&Vs[dt * 16 + m16][kt * 32 + quad * 8];
            o[rt][dt] = MFMA16(pa, vb, o[rt][dt]);
          }
        }
      __syncthreads();
    }
  }

  // normalize + write attn_out bf16 [2048][4096]
#pragma unroll
  for (int rt = 0; rt < 2; ++rt) {
    float inv[4];
#pragma unroll
    for (int r = 0; r < 4; ++r) inv[r] = 1.0f / lrun[rt][r];
#pragma unroll
    for (int dt = 0; dt < 8; ++dt)
#pragma unroll
      for (int r = 0; r < 4; ++r)
        attn[(size_t)(qrow0 + rt * 16 + quad * 4 + r) * 4096 + h * 128 +
             dt * 16 + m16] = (bf16)(o[rt][dt][r] * inv[r]);
  }
}

// ---------------------------------------------------------------------------
extern "C" void kernel_launch(void* const* d_in, const int* in_sizes, int n_in,
                              void* d_out, int out_size, void* d_ws,
                              size_t ws_size, hipStream_t stream) {
  const float* hidden = (const float*)d_in[0];
  const float* wq = (const float*)d_in[1];
  const float* wk = (const float*)d_in[2];
  const float* wv = (const float*)d_in[3];
  const float* wo = (const float*)d_in[4];
  float* out = (float*)d_out;

  bf16* qbuf = (bf16*)d_ws;                       // [2048][4096]
  bf16* kbuf = qbuf + (size_t)2048 * 4096;        // [2048][1024]
  bf16* vT = kbuf + (size_t)2048 * 1024;          // [1024][2048] (transposed)
  bf16* attnb = vT + (size_t)1024 * 2048;         // [2048][4096]

  gemm_k<float, bf16, false>
      <<<dim3(32, 16), 256, 0, stream>>>(hidden, wq, qbuf, 2048, 4096, 4096, 4096);
  gemm_k<float, bf16, false>
      <<<dim3(8, 16), 256, 0, stream>>>(hidden, wk, kbuf, 2048, 1024, 4096, 1024);
  gemm_k<float, bf16, true>
      <<<dim3(8, 16), 256, 0, stream>>>(hidden, wv, vT, 2048, 1024, 4096, 2048);
  rope_k<<<(2048 * 32 * 64 + 2048 * 8 * 64) / 256, 256, 0, stream>>>(qbuf, kbuf);
  attn_k<<<dim3(16, 32), 256, 0, stream>>>(qbuf, kbuf, vT, attnb);
  gemm_k<bf16, float, false>
      <<<dim3(32, 16), 256, 0, stream>>>(attnb, wo, out, 2048, 4096, 4096, 4096);
}

// Round 2
// 586.039 us; speedup vs baseline: 2.1227x; 2.1227x over previous
//
#include <hip/hip_runtime.h>
#include <hip/hip_bf16.h>
#include <math.h>

typedef __bf16 bf16;
typedef __attribute__((ext_vector_type(8))) __bf16 bf16x8;
typedef __attribute__((ext_vector_type(4))) __bf16 bf16x4;
typedef __attribute__((ext_vector_type(4))) float f32x4;

#define MFMA16(a, b, c) __builtin_amdgcn_mfma_f32_16x16x32_bf16(a, b, c, 0, 0, 0)

// async global->LDS, 16B per lane; lds dest must be wave-uniform base
// (HW writes base + lane*16) -- LDS tiles are therefore UNPADDED.
__device__ __forceinline__ void load16_lds(const bf16* g, bf16* l) {
  __builtin_amdgcn_global_load_lds(
      (const __attribute__((address_space(1))) void*)g,
      (__attribute__((address_space(3))) void*)l, 16, 0, 0);
}

// ---------------------------------------------------------------------------
// fp32 -> bf16 cast (hidden_states), 8 elems/thread
// ---------------------------------------------------------------------------
__global__ __launch_bounds__(256) void cast_k(const float* __restrict__ src,
                                              bf16* __restrict__ dst) {
  const size_t i = ((size_t)blockIdx.x * 256 + threadIdx.x) * 8;
  f32x4 a = *(const f32x4*)(src + i);
  f32x4 b = *(const f32x4*)(src + i + 4);
  bf16x8 h;
#pragma unroll
  for (int j = 0; j < 4; ++j) {
    h[j] = (bf16)a[j];
    h[4 + j] = (bf16)b[j];
  }
  *(bf16x8*)(dst + i) = h;
}

// ---------------------------------------------------------------------------
// Transpose + cast: src [rows][cols] fp32  ->  dst [cols][rows] bf16
// 32x32 tile via LDS; both global accesses coalesced. block (32,8).
// ---------------------------------------------------------------------------
__global__ __launch_bounds__(256) void transpose_cast_k(
    const float* __restrict__ src, bf16* __restrict__ dst, int rows,
    int cols) {
  __shared__ float tile[32][33];
  const int c0 = blockIdx.x * 32, r0 = blockIdx.y * 32;
  const int tx = threadIdx.x, ty = threadIdx.y;
#pragma unroll
  for (int i = 0; i < 32; i += 8)
    tile[ty + i][tx] = src[(size_t)(r0 + ty + i) * cols + c0 + tx];
  __syncthreads();
#pragma unroll
  for (int i = 0; i < 32; i += 8)
    dst[(size_t)(c0 + ty + i) * rows + r0 + tx] = (bf16)tile[tx][ty + i];
}

// ---------------------------------------------------------------------------
// m97-style GEMM: C[M x N] = A[M x K] @ Bt[N x K]^T, all bf16, fp32 acc.
// 128x128 tile, BK=32, 4 waves x (4x4) 16x16x32 MFMA. Staging via
// global_load_lds width=16 into unpadded As/Bs[128*32].
// EPI==0: C[row][col] (OT = bf16 or float), ldc given.
// EPI==1: fused KV epilogue -- cols <1024 to C (k, ldc), cols >=1024
//         transposed to C2 (vT[n-1024][S=2048]).
// ---------------------------------------------------------------------------
template <typename OT, int EPI>
__global__ __launch_bounds__(256, 2) void gemm_bt(const bf16* __restrict__ A,
                                                  const bf16* __restrict__ Bt,
                                                  OT* __restrict__ C,
                                                  bf16* __restrict__ C2, int M,
                                                  int N, int K, int ldc) {
  __shared__ bf16 As[128 * 32];
  __shared__ bf16 Bs[128 * 32];

  const int tid = threadIdx.x;
  const int lane = tid & 63;
  const int w = tid >> 6;
  const int quad = lane >> 4;
  const int m16 = lane & 15;
  const int wr = (w >> 1) * 64;
  const int wc = (w & 1) * 64;
  const int rowBase = blockIdx.y * 128;
  const int colBase = blockIdx.x * 128;

  f32x4 acc[4][4];
#pragma unroll
  for (int i = 0; i < 4; ++i)
#pragma unroll
    for (int j = 0; j < 4; ++j) acc[i][j] = (f32x4){0.f, 0.f, 0.f, 0.f};

  // 16B-unit decomposition of the 128x32 tile: unit u -> row u>>2, seg u&3
  const int u1 = w * 128 + lane;
  const int u2 = u1 + 64;
  const int r1 = u1 >> 2, s1 = (u1 & 3) * 8;
  const int r2 = u2 >> 2, s2 = (u2 & 3) * 8;
  const bf16* aG1 = A + (size_t)(rowBase + r1) * K + s1;
  const bf16* aG2 = A + (size_t)(rowBase + r2) * K + s2;
  const bf16* bG1 = Bt + (size_t)(colBase + r1) * K + s1;
  const bf16* bG2 = Bt + (size_t)(colBase + r2) * K + s2;
  bf16* const lA1 = As + (size_t)(w * 128) * 8;  // wave-uniform bases
  bf16* const lA2 = As + (size_t)(w * 128 + 64) * 8;
  bf16* const lB1 = Bs + (size_t)(w * 128) * 8;
  bf16* const lB2 = Bs + (size_t)(w * 128 + 64) * 8;

  for (int k0 = 0; k0 < K; k0 += 32) {
    load16_lds(aG1 + k0, lA1);
    load16_lds(aG2 + k0, lA2);
    load16_lds(bG1 + k0, lB1);
    load16_lds(bG2 + k0, lB2);
    __syncthreads();

    bf16x8 af[4], bfr[4];
#pragma unroll
    for (int mi = 0; mi < 4; ++mi)
      af[mi] = *(const bf16x8*)&As[(wr + mi * 16 + m16) * 32 + quad * 8];
#pragma unroll
    for (int ni = 0; ni < 4; ++ni)
      bfr[ni] = *(const bf16x8*)&Bs[(wc + ni * 16 + m16) * 32 + quad * 8];
#pragma unroll
    for (int mi = 0; mi < 4; ++mi)
#pragma unroll
      for (int ni = 0; ni < 4; ++ni)
        acc[mi][ni] = MFMA16(af[mi], bfr[ni], acc[mi][ni]);
    __syncthreads();
  }

  // epilogue: C/D layout col = lane&15, row = quad*4 + reg
#pragma unroll
  for (int mi = 0; mi < 4; ++mi) {
#pragma unroll
    for (int ni = 0; ni < 4; ++ni) {
      const int gr0 = rowBase + wr + mi * 16 + quad * 4;
      const int gc = colBase + wc + ni * 16 + m16;
      if constexpr (EPI == 0) {
#pragma unroll
        for (int r = 0; r < 4; ++r)
          C[(size_t)(gr0 + r) * ldc + gc] = (OT)acc[mi][ni][r];
      } else {
        if (colBase < 1024) {  // K half -> kbuf [S][1024]
#pragma unroll
          for (int r = 0; r < 4; ++r)
            C[(size_t)(gr0 + r) * ldc + gc] = (OT)acc[mi][ni][r];
        } else {  // V half -> vT [1024][2048]
          bf16x4 h;
#pragma unroll
          for (int r = 0; r < 4; ++r) h[r] = (bf16)acc[mi][ni][r];
          *(bf16x4*)&C2[(size_t)(gc - 1024) * 2048 + gr0] = h;
        }
      }
    }
  }
}

// ---------------------------------------------------------------------------
// RoPE (rotate-half, in place on bf16 q and k buffers).
// ---------------------------------------------------------------------------
__global__ __launch_bounds__(256) void rope_k(bf16* __restrict__ qb,
                                              bf16* __restrict__ kb) {
  const int NQTOT = 2048 * 32 * 64;
  const int NKTOT = 2048 * 8 * 64;
  int idx = blockIdx.x * 256 + threadIdx.x;
  bf16* buf;
  int nh, rest;
  if (idx < NQTOT) {
    buf = qb;
    nh = 32;
    rest = idx;
  } else {
    rest = idx - NQTOT;
    if (rest >= NKTOT) return;
    buf = kb;
    nh = 8;
  }
  const int j = rest & 63;
  const int hs = rest >> 6;
  const int hh = hs % nh;
  const int s = hs / nh;
  const float inv = powf(10000.0f, -(float)j * (1.0f / 64.0f));
  const float f = (float)s * inv;
  float sn, cs;
  sincosf(f, &sn, &cs);
  const size_t base = (size_t)(s * nh + hh) * 128 + j;
  const float x1 = (float)buf[base];
  const float x2 = (float)buf[base + 64];
  buf[base] = (bf16)(x1 * cs - x2 * sn);
  buf[base + 64] = (bf16)(x2 * cs + x1 * sn);
}

// ---------------------------------------------------------------------------
// Flash attention with streaming (sink + local) block mask. Unchanged from
// round 1 (correct; revisit once it's the top dispatch).
// ---------------------------------------------------------------------------
__global__ __launch_bounds__(256, 2) void attn_k(const bf16* __restrict__ q,
                                                 const bf16* __restrict__ kbuf,
                                                 const bf16* __restrict__ vT,
                                                 bf16* __restrict__ attn) {
  const int qb = blockIdx.x;
  const int h = blockIdx.y;
  const int kvh = h >> 2;
  const int tid = threadIdx.x;
  const int lane = tid & 63;
  const int w = tid >> 6;
  const int quad = lane >> 4;
  const int m16 = lane & 15;

  __shared__ bf16 Ks[64][136];
  __shared__ bf16 Vs[128][72];
  __shared__ bf16 Ps[128][72];

  const int qrow0 = qb * 128 + w * 32;

  bf16x8 qf[2][4];
#pragma unroll
  for (int rt = 0; rt < 2; ++rt)
#pragma unroll
    for (int kt = 0; kt < 4; ++kt)
      qf[rt][kt] = *(const bf16x8*)&q[(size_t)(qrow0 + rt * 16 + m16) * 4096 +
                                      h * 128 + kt * 32 + quad * 8];

  f32x4 o[2][8];
  float mrun[2][4], lrun[2][4];
#pragma unroll
  for (int rt = 0; rt < 2; ++rt) {
#pragma unroll
    for (int dt = 0; dt < 8; ++dt) o[rt][dt] = (f32x4){0.f, 0.f, 0.f, 0.f};
#pragma unroll
    for (int r = 0; r < 4; ++r) {
      mrun[rt][r] = -1e30f;
      lrun[rt][r] = 0.f;
    }
  }

  const float scale = 0.08838834764831845f;

  for (int b = 0; b <= qb; ++b) {
    if (b > 0 && (qb - b) >= 8) continue;
    for (int half = 0; half < 2; ++half) {
      const int gk0 = b * 128 + half * 64;
      {
        const int r = tid >> 2, seg = (tid & 3) * 32;
        const bf16* src = &kbuf[(size_t)(gk0 + r) * 1024 + kvh * 128 + seg];
#pragma unroll
        for (int v = 0; v < 4; ++v)
          *(bf16x8*)&Ks[r][seg + v * 8] = *(const bf16x8*)(src + v * 8);
      }
      {
        const int d = tid >> 1, seg = (tid & 1) * 32;
        const bf16* src = &vT[(size_t)(kvh * 128 + d) * 2048 + gk0 + seg];
#pragma unroll
        for (int v = 0; v < 4; ++v)
          *(bf16x8*)&Vs[d][seg + v * 8] = *(const bf16x8*)(src + v * 8);
      }
      __syncthreads();

      f32x4 sc[2][4];
#pragma unroll
      for (int rt = 0; rt < 2; ++rt)
#pragma unroll
        for (int ct = 0; ct < 4; ++ct) sc[rt][ct] = (f32x4){0.f, 0.f, 0.f, 0.f};
#pragma unroll
      for (int kt = 0; kt < 4; ++kt) {
        bf16x8 bfr[4];
#pragma unroll
        for (int ct = 0; ct < 4; ++ct)
          bfr[ct] = *(const bf16x8*)&Ks[ct * 16 + m16][kt * 32 + quad * 8];
#pragma unroll
        for (int rt = 0; rt < 2; ++rt)
#pragma unroll
          for (int ct = 0; ct < 4; ++ct)
            sc[rt][ct] = MFMA16(qf[rt][kt], bfr[ct], sc[rt][ct]);
      }

#pragma unroll
      for (int rt = 0; rt < 2; ++rt)
#pragma unroll
        for (int ct = 0; ct < 4; ++ct)
#pragma unroll
          for (int r = 0; r < 4; ++r) {
            float sv = sc[rt][ct][r] * scale;
            if (b == qb) {
              const int colg = gk0 + ct * 16 + m16;
              const int rowg = qb * 128 + w * 32 + rt * 16 + quad * 4 + r;
              if (colg > rowg) sv = -1e30f;
            }
            sc[rt][ct][r] = sv;
          }

      float mb[2][4];
#pragma unroll
      for (int rt = 0; rt < 2; ++rt)
#pragma unroll
        for (int r = 0; r < 4; ++r) {
          float m = fmaxf(fmaxf(sc[rt][0][r], sc[rt][1][r]),
                          fmaxf(sc[rt][2][r], sc[rt][3][r]));
          m = fmaxf(m, __shfl_xor(m, 1));
          m = fmaxf(m, __shfl_xor(m, 2));
          m = fmaxf(m, __shfl_xor(m, 4));
          m = fmaxf(m, __shfl_xor(m, 8));
          mb[rt][r] = m;
        }

      float alpha[2][4], ls[2][4];
#pragma unroll
      for (int rt = 0; rt < 2; ++rt)
#pragma unroll
        for (int r = 0; r < 4; ++r) {
          const float mn = fmaxf(mrun[rt][r], mb[rt][r]);
          alpha[rt][r] = __expf(mrun[rt][r] - mn);
          mrun[rt][r] = mn;
          ls[rt][r] = 0.f;
        }
#pragma unroll
      for (int rt = 0; rt < 2; ++rt)
#pragma unroll
        for (int ct = 0; ct < 4; ++ct)
#pragma unroll
          for (int r = 0; r < 4; ++r) {
            const float p = __expf(sc[rt][ct][r] - mrun[rt][r]);
            sc[rt][ct][r] = p;
            ls[rt][r] += p;
          }
#pragma unroll
      for (int rt = 0; rt < 2; ++rt)
#pragma unroll
        for (int r = 0; r < 4; ++r) {
          float s = ls[rt][r];
          s += __shfl_xor(s, 1);
          s += __shfl_xor(s, 2);
          s += __shfl_xor(s, 4);
          s += __shfl_xor(s, 8);
          lrun[rt][r] = lrun[rt][r] * alpha[rt][r] + s;
        }
#pragma unroll
      for (int rt = 0; rt < 2; ++rt)
#pragma unroll
        for (int dt = 0; dt < 8; ++dt)
#pragma unroll
          for (int r = 0; r < 4; ++r) o[rt][dt][r] *= alpha[rt][r];

#pragma unroll
      for (int rt = 0; rt < 2; ++rt)
#pragma unroll
        for (int ct = 0; ct < 4; ++ct)
#pragma unroll
          for (int r = 0; r < 4; ++r)
            Ps[w * 32 + rt * 16 + quad * 4 + r][ct * 16 + m16] =
                (bf16)sc[rt][ct][r];

#pragma unroll
      for (int rt = 0; rt < 2; ++rt)
#pragma unroll
        for (int kt = 0; kt < 2; ++kt) {
          const bf16x8 pa =
              *(const bf16x8*)&Ps[w * 32 + rt * 16 + m16][kt * 32 + quad * 8];
#pragma unroll
          for (int dt = 0; dt < 8; ++dt) {
            const bf16x8 vb =
                *(const bf16x8*)&Vs[dt * 16 + m16][kt * 32 + quad * 8];
            o[rt][dt] = MFMA16(pa, vb, o[rt][dt]);
          }
        }
      __syncthreads();
    }
  }

#pragma unroll
  for (int rt = 0; rt < 2; ++rt) {
    float inv[4];
#pragma unroll
    for (int r = 0; r < 4; ++r) inv[r] = 1.0f / lrun[rt][r];
#pragma unroll
    for (int dt = 0; dt < 8; ++dt)
#pragma unroll
      for (int r = 0; r < 4; ++r)
        attn[(size_t)(qrow0 + rt * 16 + quad * 4 + r) * 4096 + h * 128 +
             dt * 16 + m16] = (bf16)(o[rt][dt][r] * inv[r]);
  }
}

// ---------------------------------------------------------------------------
// Workspace layout (88 MB, with deliberate aliasing; stream-serial order
// makes it safe):
//   off   0 MB: hiddenB [2048][4096] bf16 (16MB)   -- dead after KV gemm
//   off  16 MB: kvT [2048][4096] bf16 (16MB)       -- dead after KV gemm
//       (woT [4096][4096] bf16 (32MB) aliases offs 0..32 after KV gemm)
//   off  32 MB: wqT [4096][4096] bf16 (32MB)       -- dead after Q gemm
//       (attnb [2048][4096] bf16 (16MB) aliases off 32 after Q gemm)
//   off  64 MB: qbuf [2048][4096] bf16 (16MB)
//   off  80 MB: kbuf [2048][1024] bf16 (4MB)
//   off  84 MB: vT  [1024][2048] bf16 (4MB)
// ---------------------------------------------------------------------------
extern "C" void kernel_launch(void* const* d_in, const int* in_sizes, int n_in,
                              void* d_out, int out_size, void* d_ws,
                              size_t ws_size, hipStream_t stream) {
  const float* hidden = (const float*)d_in[0];
  const float* wq = (const float*)d_in[1];
  const float* wk = (const float*)d_in[2];
  const float* wv = (const float*)d_in[3];
  const float* wo = (const float*)d_in[4];
  float* out = (float*)d_out;

  const size_t MB = 1024 * 1024;
  bf16* hiddenB = (bf16*)d_ws;
  bf16* kvT = (bf16*)((char*)d_ws + 16 * MB);
  bf16* woT = (bf16*)d_ws;  // aliases hiddenB+kvT (written after KV gemm)
  bf16* wqT = (bf16*)((char*)d_ws + 32 * MB);
  bf16* attnb = wqT;  // aliases wqT (written after Q gemm)
  bf16* qbuf = (bf16*)((char*)d_ws + 64 * MB);
  bf16* kbuf = (bf16*)((char*)d_ws + 80 * MB);
  bf16* vT = (bf16*)((char*)d_ws + 84 * MB);

  // --- one-time casts/transposes ---
  cast_k<<<4096, 256, 0, stream>>>(hidden, hiddenB);
  transpose_cast_k<<<dim3(128, 128), dim3(32, 8), 0, stream>>>(wq, wqT, 4096,
                                                               4096);
  transpose_cast_k<<<dim3(32, 128), dim3(32, 8), 0, stream>>>(wk, kvT, 4096,
                                                              1024);
  transpose_cast_k<<<dim3(32, 128), dim3(32, 8), 0, stream>>>(
      wv, kvT + (size_t)1024 * 4096, 4096, 1024);

  // --- projections ---
  gemm_bt<bf16, 0><<<dim3(32, 16), 256, 0, stream>>>(
      hiddenB, wqT, qbuf, nullptr, 2048, 4096, 4096, 4096);
  gemm_bt<bf16, 1><<<dim3(16, 16), 256, 0, stream>>>(
      hiddenB, kvT, kbuf, vT, 2048, 2048, 4096, 1024);

  rope_k<<<(2048 * 32 * 64 + 2048 * 8 * 64) / 256, 256, 0, stream>>>(qbuf,
                                                                     kbuf);

  // woT transpose now (overwrites hiddenB/kvT which are dead)
  transpose_cast_k<<<dim3(128, 128), dim3(32, 8), 0, stream>>>(wo, woT, 4096,
                                                               4096);

  attn_k<<<dim3(16, 32), 256, 0, stream>>>(qbuf, kbuf, vT, attnb);

  gemm_bt<float, 0><<<dim3(32, 16), 256, 0, stream>>>(
      attnb, woT, out, nullptr, 2048, 4096, 4096, 4096);
}